// Round 1
// baseline (157.355 us; speedup 1.0000x reference)
//
#include <hip/hip_runtime.h>

#define ROWS 1024
#define COLS 1024
#define NN (ROWS*COLS)

// 2-launch consolidation (R6): HALO 16 -> 16 steps/launch, k_pre folded in.
#define TILE_H 32
#define TILE_W 64
#define HALO   16
#define RH     64              // TILE_H + 2*HALO
#define RW     96              // TILE_W + 2*HALO
#define RC     (RH*RW)         // 6144 region cells
#define NT     384             // 6 waves; == NB4, every thread owns a 4x4 block
#define BR     (RH/4)          // 16
#define BC     (RW/4)          // 24
#define NB4    (BR*BC)         // 384
#define RSPR   (RW/4)          // 24 float4-strips per region row

// phi staged with a +1 ring so inv can be computed in-LDS exactly
#define APH    66              // RH + 2
#define APW    104             // RW + 8 (float4-aligned cover of the +/-1 ring)
#define APC    (APH*APW)       // 6864
#define APS    (APC/4)         // 1716 float4 strips
#define SPR    (APW/4)         // 26

static constexpr float RHOG    = 1000.0f * 9.81f;
static constexpr float INV_SEC = 1.0f / 31556926.0f;
static constexpr float FLOWC   = 0.0405f;

__device__ __forceinline__ float4 gld4(const float* __restrict__ p, int g, bool in) {
    if (in) return *reinterpret_cast<const float4*>(p + g);
    return make_float4(0.f, 0.f, 0.f, 0.f);
}
__device__ __forceinline__ int4 gldi4(const int* __restrict__ p, int g, bool in) {
    if (in) return *reinterpret_cast<const int4*>(p + g);
    return make_int4(1, 1, 1, 1);   // out-of-grid == boundary (non-core)
}

// plane layout in the LDS overlay: [buf][kind T=0,B=1,L=2,R=3][NB4]
#define PLN(b,kind) (PL + (((b) * 4 + (kind)) * NB4))

// ---- fully fused: phi/inv/runoff in-kernel + 16 halo-tiled Jacobi steps ---
// LDS timeline: AP(phi+ring 27456B)+Bv(inv 24576B) during setup, then the
// 48KB plane double-buffer overlays both (52032B total -> 2 blocks/CU).
template <bool FIRST, bool FINAL>
__global__ __launch_bounds__(NT, 3) void k_fused(
        const float* __restrict__ bed,  const float* __restrict__ pw,
        const float* __restrict__ melt, const float* __restrict__ area,
        const float* __restrict__ qin,  float* __restrict__ qout,
        const float* __restrict__ cond, const int* __restrict__ status) {
    __shared__ __align__(16) float lds[APC + RC];          // 52032 B
    float*  AP = lds;                                      // phi  (r0-1, c0-4), 66x104
    float*  Bv = lds + APC;                                // inv  (r0,   c0  ), 64x96
    float4* PL = reinterpret_cast<float4*>(lds);           // overlays AP/Bv after setup

    const int tid = threadIdx.x;
    const int r0 = (int)blockIdx.y * TILE_H - HALO;
    const int c0 = (int)blockIdx.x * TILE_W - HALO;

    // ---- stage phi = RHOG*bed + pw over region + ring ---------------------
#pragma unroll
    for (int k = 0; k < 5; ++k) {
        int sidx = tid + k * NT;
        if (sidx < APS) {
            int sr = sidx / SPR, sc4 = (sidx - sr * SPR) * 4;
            int gr = r0 - 1 + sr, gc = c0 - 4 + sc4;
            bool in = (gr >= 0) & (gr < ROWS) & (gc >= 0) & (gc < COLS);
            int g = gr * COLS + gc;
            float4 b4 = gld4(bed, g, in);
            float4 p4 = gld4(pw,  g, in);
            float4 ph;
            ph.x = fmaf(RHOG, b4.x, p4.x);
            ph.y = fmaf(RHOG, b4.y, p4.y);
            ph.z = fmaf(RHOG, b4.z, p4.z);
            ph.w = fmaf(RHOG, b4.w, p4.w);
            *reinterpret_cast<float4*>(&AP[sr * APW + sc4]) = ph;
        }
    }
    __syncthreads();

    // ---- inv = (core && t>0) ? 1/t : 0 over the full region ---------------
    // Ring guarantees exact neighbor phi even for region-rim cells (their inv
    // feeds depth-1 cells' weights). Out-of-grid neighbors only exist for
    // perimeter (non-core) cells, where inv is 0 regardless.
#pragma unroll
    for (int k = 0; k < 4; ++k) {
        int sidx = tid + k * NT;                  // exactly RC/4 strips
        int sr = sidx / RSPR, sc4 = (sidx - sr * RSPR) * 4;
        int x = (sr + 1) * APW + sc4 + 4;
        float4 pc = *reinterpret_cast<const float4*>(&AP[x]);
        float4 pu = *reinterpret_cast<const float4*>(&AP[x - APW]);
        float4 pd = *reinterpret_cast<const float4*>(&AP[x + APW]);
        float pl = AP[x - 1], pr = AP[x + 4];
        float t0 = ((fmaxf(pc.x - pl,   0.f) + fmaxf(pc.x - pc.y, 0.f))
                  +  fmaxf(pc.x - pu.x, 0.f)) + fmaxf(pc.x - pd.x, 0.f);
        float t1 = ((fmaxf(pc.y - pc.x, 0.f) + fmaxf(pc.y - pc.z, 0.f))
                  +  fmaxf(pc.y - pu.y, 0.f)) + fmaxf(pc.y - pd.y, 0.f);
        float t2 = ((fmaxf(pc.z - pc.y, 0.f) + fmaxf(pc.z - pc.w, 0.f))
                  +  fmaxf(pc.z - pu.z, 0.f)) + fmaxf(pc.z - pd.z, 0.f);
        float t3 = ((fmaxf(pc.w - pc.z, 0.f) + fmaxf(pc.w - pr,   0.f))
                  +  fmaxf(pc.w - pu.w, 0.f)) + fmaxf(pc.w - pd.w, 0.f);
        int gr = r0 + sr, gc = c0 + sc4;
        bool in = (gr >= 0) & (gr < ROWS) & (gc >= 0) & (gc < COLS);
        int4 st = gldi4(status, gr * COLS + gc, in);
        float4 iv;
        iv.x = (st.x == 0 && t0 > 0.f) ? 1.f / t0 : 0.f;
        iv.y = (st.y == 0 && t1 > 0.f) ? 1.f / t1 : 0.f;
        iv.z = (st.z == 0 && t2 > 0.f) ? 1.f / t2 : 0.f;
        iv.w = (st.w == 0 && t3 > 0.f) ? 1.f / t3 : 0.f;
        *reinterpret_cast<float4*>(&Bv[sr * RW + sc4]) = iv;
    }
    __syncthreads();

    // ---- weights into registers (recompute-once, R5 scheme) ---------------
    const int br = tid / BC, bc = tid - (tid / BC) * BC;
    const int rr0 = 4 * br, cc0 = 4 * bc;
    const bool inter = (br >= 4) & (br <= BR - 5) & (bc >= 4) & (bc <= BC - 5);

    float wW[4][4], wE[4][4], wN[4][4], wS[4][4];
    float q[4][4], ro[4][4];
    int dr_[4], dc_[4];

#pragma unroll
    for (int i = 0; i < 4; ++i) {
        int rr = rr0 + i;
        int xp = (rr + 1) * APW + cc0 + 4;
        float4 pc = *reinterpret_cast<const float4*>(&AP[xp]);
        float4 pu = *reinterpret_cast<const float4*>(&AP[xp - APW]);
        float4 pd = *reinterpret_cast<const float4*>(&AP[xp + APW]);
        float pl = AP[xp - 1], pr = AP[xp + 4];
        int xb = rr * RW + cc0;
        float4 ic = *reinterpret_cast<const float4*>(&Bv[xb]);
        float4 iu = *reinterpret_cast<const float4*>(&Bv[(rr > 0)      ? xb - RW : xb]);
        float4 id = *reinterpret_cast<const float4*>(&Bv[(rr < RH - 1) ? xb + RW : xb]);
        float il = (cc0 > 0)      ? Bv[xb - 1] : 0.f;
        float ir = (cc0 < RW - 4) ? Bv[xb + 4] : 0.f;
        // rim rows/cols get clamped inv reads -> wrong weights, but those
        // cells are frozen from step 0 (depth 0) and never apply them.
        wN[i][0] = fmaxf(pu.x - pc.x, 0.f) * iu.x;
        wN[i][1] = fmaxf(pu.y - pc.y, 0.f) * iu.y;
        wN[i][2] = fmaxf(pu.z - pc.z, 0.f) * iu.z;
        wN[i][3] = fmaxf(pu.w - pc.w, 0.f) * iu.w;
        wS[i][0] = fmaxf(pd.x - pc.x, 0.f) * id.x;
        wS[i][1] = fmaxf(pd.y - pc.y, 0.f) * id.y;
        wS[i][2] = fmaxf(pd.z - pc.z, 0.f) * id.z;
        wS[i][3] = fmaxf(pd.w - pc.w, 0.f) * id.w;
        wW[i][0] = fmaxf(pl   - pc.x, 0.f) * il;
        wW[i][1] = fmaxf(pc.x - pc.y, 0.f) * ic.x;
        wW[i][2] = fmaxf(pc.y - pc.z, 0.f) * ic.y;
        wW[i][3] = fmaxf(pc.z - pc.w, 0.f) * ic.z;
        wE[i][0] = fmaxf(pc.y - pc.x, 0.f) * ic.y;
        wE[i][1] = fmaxf(pc.z - pc.y, 0.f) * ic.z;
        wE[i][2] = fmaxf(pc.w - pc.z, 0.f) * ic.w;
        wE[i][3] = fmaxf(pr   - pc.w, 0.f) * ir;
    }
#pragma unroll
    for (int i = 0; i < 4; ++i) {
        int rr = rr0 + i, cc = cc0 + i;
        dr_[i] = min(rr, RH - 1 - rr);
        dc_[i] = min(cc, RW - 1 - cc);
    }
    // runoff + q0 straight from global to registers
#pragma unroll
    for (int i = 0; i < 4; ++i) {
        int gr = r0 + rr0 + i, gc = c0 + cc0;
        bool in = (gr >= 0) & (gr < ROWS) & (gc >= 0) & (gc < COLS);
        int g = gr * COLS + gc;
        float4 m4 = gld4(melt, g, in);
        float4 a4 = gld4(area, g, in);
        ro[i][0] = m4.x * a4.x * INV_SEC;
        ro[i][1] = m4.y * a4.y * INV_SEC;
        ro[i][2] = m4.z * a4.z * INV_SEC;
        ro[i][3] = m4.w * a4.w * INV_SEC;
        if (FIRST) {
            q[i][0] = ro[i][0]; q[i][1] = ro[i][1];
            q[i][2] = ro[i][2]; q[i][3] = ro[i][3];
        } else {
            float4 q4 = gld4(qin, g, in);
            q[i][0] = q4.x; q[i][1] = q4.y; q[i][2] = q4.z; q[i][3] = q4.w;
        }
    }
    __syncthreads();   // all AP/Bv reads done before the plane overlay is written

    PLN(0,0)[tid] = make_float4(q[0][0], q[0][1], q[0][2], q[0][3]);
    PLN(0,1)[tid] = make_float4(q[3][0], q[3][1], q[3][2], q[3][3]);
    PLN(0,2)[tid] = make_float4(q[0][0], q[1][0], q[2][0], q[3][0]);
    PLN(0,3)[tid] = make_float4(q[0][3], q[1][3], q[2][3], q[3][3]);
    __syncthreads();

    // ---- 16 Jacobi steps; only 4x4-block edges touch LDS ------------------
    for (int s = 0; s < HALO; ++s) {
        const int pp = s & 1, pn = pp ^ 1;
        float4 up = PLN(pp,1)[(br > 0)      ? tid - BC : tid];
        float4 dn = PLN(pp,0)[(br < BR - 1) ? tid + BC : tid];
        float4 lf = PLN(pp,3)[(bc > 0)      ? tid - 1  : tid];
        float4 rt = PLN(pp,2)[(bc < BC - 1) ? tid + 1  : tid];
        float upv[4] = {up.x, up.y, up.z, up.w};
        float dnv[4] = {dn.x, dn.y, dn.z, dn.w};
        float lfv[4] = {lf.x, lf.y, lf.z, lf.w};
        float rtv[4] = {rt.x, rt.y, rt.z, rt.w};
        float nq[4][4];
#pragma unroll
        for (int i = 0; i < 4; ++i)
#pragma unroll
            for (int j = 0; j < 4; ++j) {
                float uv = (i > 0) ? q[i - 1][j] : upv[j];
                float dv = (i < 3) ? q[i + 1][j] : dnv[j];
                float lv = (j > 0) ? q[i][j - 1] : lfv[i];
                float rv = (j < 3) ? q[i][j + 1] : rtv[i];
                float a = ro[i][j];
                a = fmaf(wW[i][j], lv, a);
                a = fmaf(wE[i][j], rv, a);
                a = fmaf(wN[i][j], uv, a);
                a = fmaf(wS[i][j], dv, a);
                nq[i][j] = a;
            }
        if (!inter) {      // border blocks: freeze cells past their depth
#pragma unroll
            for (int i = 0; i < 4; ++i)
#pragma unroll
                for (int j = 0; j < 4; ++j)
                    nq[i][j] = (s < min(dr_[i], dc_[j])) ? nq[i][j] : q[i][j];
        }
#pragma unroll
        for (int i = 0; i < 4; ++i)
#pragma unroll
            for (int j = 0; j < 4; ++j) q[i][j] = nq[i][j];
        PLN(pn,0)[tid] = make_float4(q[0][0], q[0][1], q[0][2], q[0][3]);
        PLN(pn,1)[tid] = make_float4(q[3][0], q[3][1], q[3][2], q[3][3]);
        PLN(pn,2)[tid] = make_float4(q[0][0], q[1][0], q[2][0], q[3][0]);
        PLN(pn,3)[tid] = make_float4(q[0][3], q[1][3], q[2][3], q[3][3]);
        __syncthreads();
    }

    // interior blocks == the 32x64 output tile exactly
    if (inter) {
#pragma unroll
        for (int i = 0; i < 4; ++i) {
            int g = (r0 + rr0 + i) * COLS + (c0 + cc0);
            if (FINAL) {
                float4 c4 = *reinterpret_cast<const float4*>(cond + g);
                int4 st   = *reinterpret_cast<const int4*>(status + g);
                float4 o;
                float t;
                t = q[i][0] * FLOWC * (c4.x * sqrtf(sqrtf(c4.x))); o.x = (st.x == 0) ? t * t : 0.f;
                t = q[i][1] * FLOWC * (c4.y * sqrtf(sqrtf(c4.y))); o.y = (st.y == 0) ? t * t : 0.f;
                t = q[i][2] * FLOWC * (c4.z * sqrtf(sqrtf(c4.z))); o.z = (st.z == 0) ? t * t : 0.f;
                t = q[i][3] * FLOWC * (c4.w * sqrtf(sqrtf(c4.w))); o.w = (st.w == 0) ? t * t : 0.f;
                *reinterpret_cast<float4*>(qout + g) = o;
            } else {
                *reinterpret_cast<float4*>(qout + g) =
                    make_float4(q[i][0], q[i][1], q[i][2], q[i][3]);
            }
        }
    }
}

extern "C" void kernel_launch(void* const* d_in, const int* in_sizes, int n_in,
                              void* d_out, int out_size, void* d_ws, size_t ws_size,
                              hipStream_t stream) {
    const float* melt   = (const float*)d_in[0];
    const float* bed    = (const float*)d_in[1];
    const float* pw     = (const float*)d_in[2];
    const float* area   = (const float*)d_in[3];
    const float* cond   = (const float*)d_in[4];
    const int*   status = (const int*)d_in[5];
    float* out = (float*)d_out;
    float* qA  = (float*)d_ws;           // 4 MB intermediate q^16

    dim3 grid(COLS / TILE_W, ROWS / TILE_H), block(NT);
    k_fused<true,  false><<<grid, block, 0, stream>>>(bed, pw, melt, area, nullptr, qA, nullptr, status);
    k_fused<false, true ><<<grid, block, 0, stream>>>(bed, pw, melt, area, qA, out, cond, status);
}

// Round 2
// 144.229 us; speedup vs baseline: 1.0910x; 1.0910x over previous
//
#include <hip/hip_runtime.h>

#define ROWS 1024
#define COLS 1024
#define NN (ROWS*COLS)

// R7: round-0 structure (k_pre + 4x8-step launches), but 2x4 cells/thread
// (16 waves/CU instead of 8), freeze logic removed (cone argument), and
// phi/inv staging overlaid with the plane double-buffer.
#define TILE_H 32
#define TILE_W 64
#define HALO   8
#define RH     48              // TILE_H + 2*HALO
#define RW     80              // TILE_W + 2*HALO
#define RC     (RH*RW)         // 3840 region cells
#define NT     512             // 8 waves
#define BR     (RH/2)          // 24 block-rows of 2x4 cells
#define BC     (RW/4)          // 20 block-cols
#define NB     (BR*BC)         // 480 active threads
#define NSTRIP (RC/4)          // 960 float4 strips
#define SPR    (RW/4)          // 20 strips per region row

static constexpr float RHOG    = 1000.0f * 9.81f;
static constexpr float INV_SEC = 1.0f / 31556926.0f;
static constexpr float FLOWC   = 0.0405f;

__device__ __forceinline__ float4 gld4(const float* __restrict__ p, int g, bool in) {
    if (in) return *reinterpret_cast<const float4*>(p + g);
    return make_float4(0.f, 0.f, 0.f, 0.f);
}

// ---- prologue: phi, inv_total, runoff (unchanged from the 141.8 winner) ---
__global__ __launch_bounds__(256) void k_pre(
        const float* __restrict__ bed, const float* __restrict__ pw,
        const int* __restrict__ status,
        const float* __restrict__ melt, const float* __restrict__ area,
        float* __restrict__ phi, float* __restrict__ inv,
        float* __restrict__ runoff) {
    int i = blockIdx.x * 256 + threadIdx.x;
    int r = i >> 10, c = i & (COLS - 1);
    float p = RHOG * bed[i] + pw[i];
    float t = 0.f;
    if (c > 0)        t += fmaxf(p - (RHOG * bed[i - 1]    + pw[i - 1]),    0.f);
    if (c < COLS - 1) t += fmaxf(p - (RHOG * bed[i + 1]    + pw[i + 1]),    0.f);
    if (r > 0)        t += fmaxf(p - (RHOG * bed[i - COLS] + pw[i - COLS]), 0.f);
    if (r < ROWS - 1) t += fmaxf(p - (RHOG * bed[i + COLS] + pw[i + COLS]), 0.f);
    phi[i]    = p;
    inv[i]    = (status[i] == 0 && t > 0.f) ? (1.f / t) : 0.f;
    runoff[i] = melt[i] * area[i] * INV_SEC;
}

// LDS overlay layout (floats):
//   [0,     3840)  plT[2][NB] float4   (also: A = phi staging, dead after weights)
//   [3840,  7680)  plB[2][NB] float4   (also: Bv = inv staging)
//   [7680,  9600)  plL[2][NB] float2
//   [9600, 11520)  plR[2][NB] float2
#define LDSF   11520           // 46080 B

// ---- fused 8-step halo-tiled Jacobi, 2x4 cells per thread -----------------
template <bool FIRST, bool FINAL>
__global__ __launch_bounds__(NT, 2) void k_fused(
        const float* __restrict__ phi_g, const float* __restrict__ inv_g,
        const float* __restrict__ run_g, const float* __restrict__ qin,
        float* __restrict__ qout,
        const float* __restrict__ cond, const int* __restrict__ status) {
    __shared__ __align__(16) float lds[LDSF];
    float*  A  = lds;                                       // phi staging
    float*  Bv = lds + RC;                                  // inv staging
    float4* pT = reinterpret_cast<float4*>(lds);            // [buf*NB + t]
    float4* pB = reinterpret_cast<float4*>(lds) + 2 * NB;
    float2* pL = reinterpret_cast<float2*>(lds + 7680);
    float2* pR = reinterpret_cast<float2*>(lds + 9600);

    const int tid = threadIdx.x;
    const int r0 = (int)blockIdx.y * TILE_H - HALO;
    const int c0 = (int)blockIdx.x * TILE_W - HALO;

    const bool active = (tid < NB);
    const int br = tid / BC, bc = tid - (tid / BC) * BC;
    const int rr0 = 2 * br, cc0 = 4 * bc;
    const bool inter = (br >= 4) & (br <= BR - 5) & (bc >= 2) & (bc <= BC - 3);

    float q[2][4], ro[2][4];

    // runoff + q0 straight from global to registers (issue before barrier)
    if (active) {
#pragma unroll
        for (int i = 0; i < 2; ++i) {
            int gr = r0 + rr0 + i, gc = c0 + cc0;
            bool in = (gr >= 0) & (gr < ROWS) & (gc >= 0) & (gc < COLS);
            int g = gr * COLS + gc;
            float4 r4 = gld4(run_g, g, in);
            ro[i][0] = r4.x; ro[i][1] = r4.y; ro[i][2] = r4.z; ro[i][3] = r4.w;
            float4 q4 = FIRST ? r4 : gld4(qin, g, in);
            q[i][0] = q4.x; q[i][1] = q4.y; q[i][2] = q4.z; q[i][3] = q4.w;
        }
    }

    // stage phi, inv (all 512 threads, 960 strips)
#pragma unroll
    for (int k = 0; k < 2; ++k) {
        int sidx = tid + k * NT;
        if (sidx < NSTRIP) {
            int sr = sidx / SPR, sc4 = (sidx - sr * SPR) * 4;
            int gr = r0 + sr, gc = c0 + sc4;
            bool in = (gr >= 0) & (gr < ROWS) & (gc >= 0) & (gc < COLS);
            int g = gr * COLS + gc;
            *reinterpret_cast<float4*>(&A[sr * RW + sc4])  = gld4(phi_g, g, in);
            *reinterpret_cast<float4*>(&Bv[sr * RW + sc4]) = gld4(inv_g, g, in);
        }
    }
    __syncthreads();

    // weights into registers; clamped edge reads yield weight 0 (rim cells'
    // values go wrong past their depth, but the cone argument keeps every
    // output-tile cell exact through step HALO -- no freezing needed).
    float wW[2][4], wE[2][4], wN[2][4], wS[2][4];
    if (active) {
#pragma unroll
        for (int i = 0; i < 2; ++i) {
            int rr = rr0 + i;
            int x = rr * RW + cc0;
            float4 pc = *reinterpret_cast<const float4*>(&A[x]);
            float4 ic = *reinterpret_cast<const float4*>(&Bv[x]);
            int xu = (rr > 0)      ? x - RW : x;
            int xd = (rr < RH - 1) ? x + RW : x;
            float4 pu = *reinterpret_cast<const float4*>(&A[xu]);
            float4 iu = *reinterpret_cast<const float4*>(&Bv[xu]);
            float4 pd = *reinterpret_cast<const float4*>(&A[xd]);
            float4 id = *reinterpret_cast<const float4*>(&Bv[xd]);
            float pl = (cc0 > 0)      ? A[x - 1]  : pc.x;
            float il = (cc0 > 0)      ? Bv[x - 1] : 0.f;
            float pr = (cc0 < RW - 4) ? A[x + 4]  : pc.w;
            float ir = (cc0 < RW - 4) ? Bv[x + 4] : 0.f;
            wN[i][0] = fmaxf(pu.x - pc.x, 0.f) * iu.x;
            wN[i][1] = fmaxf(pu.y - pc.y, 0.f) * iu.y;
            wN[i][2] = fmaxf(pu.z - pc.z, 0.f) * iu.z;
            wN[i][3] = fmaxf(pu.w - pc.w, 0.f) * iu.w;
            wS[i][0] = fmaxf(pd.x - pc.x, 0.f) * id.x;
            wS[i][1] = fmaxf(pd.y - pc.y, 0.f) * id.y;
            wS[i][2] = fmaxf(pd.z - pc.z, 0.f) * id.z;
            wS[i][3] = fmaxf(pd.w - pc.w, 0.f) * id.w;
            wW[i][0] = fmaxf(pl   - pc.x, 0.f) * il;
            wW[i][1] = fmaxf(pc.x - pc.y, 0.f) * ic.x;
            wW[i][2] = fmaxf(pc.y - pc.z, 0.f) * ic.y;
            wW[i][3] = fmaxf(pc.z - pc.w, 0.f) * ic.z;
            wE[i][0] = fmaxf(pc.y - pc.x, 0.f) * ic.y;
            wE[i][1] = fmaxf(pc.z - pc.y, 0.f) * ic.z;
            wE[i][2] = fmaxf(pc.w - pc.z, 0.f) * ic.w;
            wE[i][3] = fmaxf(pr   - pc.w, 0.f) * ir;
        }
    }
    __syncthreads();   // A/Bv dead; planes may now overwrite them

    if (active) {
        pT[tid]          = make_float4(q[0][0], q[0][1], q[0][2], q[0][3]);
        pB[tid]          = make_float4(q[1][0], q[1][1], q[1][2], q[1][3]);
        pL[tid]          = make_float2(q[0][0], q[1][0]);
        pR[tid]          = make_float2(q[0][3], q[1][3]);
    }
    __syncthreads();

    // 8 Jacobi steps; only 2x4-block edges touch LDS, no freeze path
    for (int s = 0; s < HALO; ++s) {
        const int pp = s & 1, pn = pp ^ 1;
        if (active) {
            float4 up = pB[pp * NB + ((br > 0)      ? tid - BC : tid)];
            float4 dn = pT[pp * NB + ((br < BR - 1) ? tid + BC : tid)];
            float2 lf = pR[pp * NB + ((bc > 0)      ? tid - 1  : tid)];
            float2 rt = pL[pp * NB + ((bc < BC - 1) ? tid + 1  : tid)];
            float upv[4] = {up.x, up.y, up.z, up.w};
            float dnv[4] = {dn.x, dn.y, dn.z, dn.w};
            float lfv[2] = {lf.x, lf.y};
            float rtv[2] = {rt.x, rt.y};
            float nq[2][4];
#pragma unroll
            for (int i = 0; i < 2; ++i)
#pragma unroll
                for (int j = 0; j < 4; ++j) {
                    float uv = (i > 0) ? q[0][j] : upv[j];
                    float dv = (i < 1) ? q[1][j] : dnv[j];
                    float lv = (j > 0) ? q[i][j - 1] : lfv[i];
                    float rv = (j < 3) ? q[i][j + 1] : rtv[i];
                    float a = ro[i][j];
                    a = fmaf(wW[i][j], lv, a);
                    a = fmaf(wE[i][j], rv, a);
                    a = fmaf(wN[i][j], uv, a);
                    a = fmaf(wS[i][j], dv, a);
                    nq[i][j] = a;
                }
#pragma unroll
            for (int i = 0; i < 2; ++i)
#pragma unroll
                for (int j = 0; j < 4; ++j) q[i][j] = nq[i][j];
            pT[pn * NB + tid] = make_float4(q[0][0], q[0][1], q[0][2], q[0][3]);
            pB[pn * NB + tid] = make_float4(q[1][0], q[1][1], q[1][2], q[1][3]);
            pL[pn * NB + tid] = make_float2(q[0][0], q[1][0]);
            pR[pn * NB + tid] = make_float2(q[0][3], q[1][3]);
        }
        __syncthreads();
    }

    // interior blocks == the 32x64 output tile exactly
    if (active && inter) {
#pragma unroll
        for (int i = 0; i < 2; ++i) {
            int g = (r0 + rr0 + i) * COLS + (c0 + cc0);
            if (FINAL) {
                float4 c4 = *reinterpret_cast<const float4*>(cond + g);
                int4 st   = *reinterpret_cast<const int4*>(status + g);
                float4 o;
                float t;
                t = q[i][0] * FLOWC * (c4.x * sqrtf(sqrtf(c4.x))); o.x = (st.x == 0) ? t * t : 0.f;
                t = q[i][1] * FLOWC * (c4.y * sqrtf(sqrtf(c4.y))); o.y = (st.y == 0) ? t * t : 0.f;
                t = q[i][2] * FLOWC * (c4.z * sqrtf(sqrtf(c4.z))); o.z = (st.z == 0) ? t * t : 0.f;
                t = q[i][3] * FLOWC * (c4.w * sqrtf(sqrtf(c4.w))); o.w = (st.w == 0) ? t * t : 0.f;
                *reinterpret_cast<float4*>(qout + g) = o;
            } else {
                *reinterpret_cast<float4*>(qout + g) =
                    make_float4(q[i][0], q[i][1], q[i][2], q[i][3]);
            }
        }
    }
}

extern "C" void kernel_launch(void* const* d_in, const int* in_sizes, int n_in,
                              void* d_out, int out_size, void* d_ws, size_t ws_size,
                              hipStream_t stream) {
    const float* melt   = (const float*)d_in[0];
    const float* bed    = (const float*)d_in[1];
    const float* pw     = (const float*)d_in[2];
    const float* area   = (const float*)d_in[3];
    const float* cond   = (const float*)d_in[4];
    const int*   status = (const int*)d_in[5];
    float* out = (float*)d_out;

    char* ws = (char*)d_ws;
    float* phi    = (float*)(ws);                 //  4 MB
    float* inv    = (float*)(ws + 4ull  * NN);    //  4 MB
    float* runoff = (float*)(ws + 8ull  * NN);    //  4 MB
    float* qA     = (float*)(ws + 12ull * NN);    //  4 MB
    float* qB     = (float*)(ws + 16ull * NN);    //  4 MB (20 MB total)

    k_pre<<<dim3(NN / 256), dim3(256), 0, stream>>>(bed, pw, status, melt, area,
                                                    phi, inv, runoff);

    dim3 grid(COLS / TILE_W, ROWS / TILE_H), block(NT);
    k_fused<true,  false><<<grid, block, 0, stream>>>(phi, inv, runoff, runoff, qA, nullptr, nullptr);
    k_fused<false, false><<<grid, block, 0, stream>>>(phi, inv, runoff, qA, qB, nullptr, nullptr);
    k_fused<false, false><<<grid, block, 0, stream>>>(phi, inv, runoff, qB, qA, nullptr, nullptr);
    k_fused<false, true ><<<grid, block, 0, stream>>>(phi, inv, runoff, qA, out, cond, status);
}